// Round 10
// baseline (159.846 us; speedup 1.0000x reference)
//
#include <hip/hip_runtime.h>
#include <hip/hip_bf16.h>

typedef __attribute__((ext_vector_type(8)))  __bf16 bf16x8;
typedef __attribute__((ext_vector_type(16))) float  f32x16;

#define N_TILES   72          // 2304 / 32
#define W2F_ELEMS (72*4*64*8) // 147456 bf16 (tile = 2048 bf16 = 4096 B)
#define W1F_ELEMS (2*4*64*8)  // 4096 bf16

__device__ __forceinline__ void gload_lds16(const void* g, void* l) {
    __builtin_amdgcn_global_load_lds(
        (const __attribute__((address_space(1))) unsigned int*)g,
        (__attribute__((address_space(3))) unsigned int*)l, 16, 0, 0);
}

__device__ __forceinline__ unsigned pk_bf16(float a, float b) {
    unsigned r;
    asm("v_cvt_pk_bf16_f32 %0, %1, %2" : "=v"(r) : "v"(a), "v"(b));
    return r;
}

// ---------------- prep: pack W2^T/8 and W1^T/8 (bf16) in MFMA A-fragment order ----------------
// A-frag order: [tile][ks][lane][j] holds A[row = 32*tile + (lane&31)][k = 16*ks + 8*(lane>>5) + j]
// Blocks 0..71: tile t, fully coalesced W2 row reads. Block 72: W1F (tiny).
__global__ __launch_bounds__(256) void equiconv_prep(const float* __restrict__ W1,
                                                     const float* __restrict__ W2,
                                                     __bf16* __restrict__ W1F,
                                                     __bf16* __restrict__ W2F) {
    const int b = blockIdx.x;
    const int tid = threadIdx.x;
    if (b < 72) {
        const int c   = tid >> 2;          // W2 row 0..63
        const int grp = tid & 3;           // octet of columns
        const float* src = W2 + (size_t)c * 2304 + 32 * b + 8 * grp;
        float4 u0 = *(const float4*)src;
        float4 u1 = *(const float4*)(src + 4);
        const int ks  = c >> 4;
        const int hib = (c >> 3) & 1;
        const int j   = c & 7;
        __bf16* dst = W2F + ((size_t)(b * 4 + ks) * 64 + 32 * hib + 8 * grp) * 8 + j;
        dst[0 * 8] = (__bf16)(u0.x * 0.125f);
        dst[1 * 8] = (__bf16)(u0.y * 0.125f);
        dst[2 * 8] = (__bf16)(u0.z * 0.125f);
        dst[3 * 8] = (__bf16)(u0.w * 0.125f);
        dst[4 * 8] = (__bf16)(u1.x * 0.125f);
        dst[5 * 8] = (__bf16)(u1.y * 0.125f);
        dst[6 * 8] = (__bf16)(u1.z * 0.125f);
        dst[7 * 8] = (__bf16)(u1.w * 0.125f);
    } else {
        for (int i2 = tid; i2 < W1F_ELEMS; i2 += 256) {
            int j  = i2 & 7;
            int ln = (i2 >> 3) & 63;
            int ks = (i2 >> 9) & 3;
            int mt = i2 >> 11;
            int c  = 32 * mt + (ln & 31);      // W1 output col (0..63)
            int in = ks * 16 + 8 * (ln >> 5) + j;
            W1F[i2] = (__bf16)(W1[in * 64 + c] * 0.125f);
        }
    }
}

// ---------------- main fused kernel: 128 elements / block (4 waves x 32 elems) ----------------
// LDS 73728 B: [0 .. 6144) floats = 6-slot staging ring (6 x 4096 B);
//              [6144 .. 18432) floats = CF[c=96][el=128] coefficient array
//                (address depends only on el -> wave reads are broadcast, conflict-free).
// CF c-map: 0..31 = x1_0[u]; 32..47 = cb1[u]; 48..95 = x1_1 flat (3u+k).
// Output staging (after loop) reuses floats [0 .. 10368) as [el=128][81].
#define CFld(c) smemf[6144 + (c) * 128 + eLoc]

__global__ __launch_bounds__(256, 2) void equiconv_main(const float* __restrict__ fea_in1,
                                                        const float* __restrict__ fea_in2,
                                                        const float* __restrict__ fea_w,
                                                        const __bf16* __restrict__ W2F,
                                                        const __bf16* __restrict__ W1F,
                                                        float* __restrict__ out) {
    __shared__ __align__(16) float smemf[18432];   // 73728 B
    __bf16* RING = (__bf16*)smemf;
    char*   rgb  = (char*)smemf;
    const char* w2b = (const char*)W2F;

    const int tid  = threadIdx.x;
    const int lane = tid & 63;
    const int wv   = tid >> 6;     // wave 0..3
    const int l31  = lane & 31;
    const int hi   = lane >> 5;    // half-wave
    const int eBlk = blockIdx.x * 128;
    const int eLoc = wv * 32 + l31;       // element owned by this lane (0..127)

    // stage tile T (4096 B) into ring slot T%6: 256 threads x one global_load_lds(16B)
#define STAGE(T) {                                                                \
        const char* _s = w2b + ((size_t)(T) << 12) + wv * 1024 + (lane << 4);     \
        char* _d = rgb + (((T) % 6) << 12) + wv * 1024;                           \
        gload_lds16(_s, _d); }

    // ---- prefetch tile groups 0,1 (oldest in vmcnt queue; drained by pre-loop sync) ----
    STAGE(0); STAGE(1); STAGE(2); STAGE(3);

    // ---- CF staging: thread el (<128) loads its element row, writes CF (2-way bank = free) ----
    if (tid < 128) {
        const float* r1 = fea_in1 + (size_t)(eBlk + tid) * 80;
        // x1_0 -> CF[0..31]
#pragma unroll
        for (int q = 0; q < 8; ++q) {
            float4 v = *(const float4*)(r1 + 4 * q);
            smemf[6144 + (4 * q + 0) * 128 + tid] = v.x;
            smemf[6144 + (4 * q + 1) * 128 + tid] = v.y;
            smemf[6144 + (4 * q + 2) * 128 + tid] = v.z;
            smemf[6144 + (4 * q + 3) * 128 + tid] = v.w;
        }
        // x1_1 -> CF[48..95], keep values for cb1
        float xv[48];
#pragma unroll
        for (int q = 0; q < 12; ++q) {
            float4 v = *(const float4*)(r1 + 32 + 4 * q);
            xv[4 * q + 0] = v.x; xv[4 * q + 1] = v.y; xv[4 * q + 2] = v.z; xv[4 * q + 3] = v.w;
            smemf[6144 + (48 + 4 * q + 0) * 128 + tid] = v.x;
            smemf[6144 + (48 + 4 * q + 1) * 128 + tid] = v.y;
            smemf[6144 + (48 + 4 * q + 2) * 128 + tid] = v.z;
            smemf[6144 + (48 + 4 * q + 3) * 128 + tid] = v.w;
        }
        const float4 f2o = *(const float4*)(fea_in2 + (size_t)(eBlk + tid) * 4);
        const float c110 = 0.10206207261596577f; // pw110*ISQRT3 = sqrt(1/96)
#pragma unroll
        for (int u = 0; u < 16; ++u)
            smemf[6144 + (32 + u) * 128 + tid] =
                c110 * (xv[3 * u] * f2o.y + xv[3 * u + 1] * f2o.z + xv[3 * u + 2] * f2o.w);
    }

    // ---- per-lane x2 scalars ----
    const float4 f2v = *(const float4*)(fea_in2 + (size_t)(eBlk + eLoc) * 4);
    const float sA0  = 0.125f * f2v.x;               // pw00 * x2_0
    const float s101 = 0.17677669529663687f * f2v.x; // sqrt(1/32) * x2_0

    // ---- GEMM1: x[c][e] = sum_in (W1[in][c]/8) * feaw[e][in]; h = 1.679*silu(x) ----
    const f32x16 Z16 = {0,0,0,0,0,0,0,0,0,0,0,0,0,0,0,0};
    bf16x8 hfr0, hfr1, hfr2, hfr3;
    {
        bf16x8 bw[4];
        const float* pw = fea_w + (size_t)(eBlk + eLoc) * 64 + hi * 8;
#pragma unroll
        for (int ks = 0; ks < 4; ++ks) {
            float4 u0 = *(const float4*)(pw + ks * 16);
            float4 u1 = *(const float4*)(pw + ks * 16 + 4);
            bf16x8 b;
            b[0] = (__bf16)u0.x; b[1] = (__bf16)u0.y; b[2] = (__bf16)u0.z; b[3] = (__bf16)u0.w;
            b[4] = (__bf16)u1.x; b[5] = (__bf16)u1.y; b[6] = (__bf16)u1.z; b[7] = (__bf16)u1.w;
            bw[ks] = b;
        }
        f32x16 h0 = Z16, h1 = Z16;
#pragma unroll
        for (int ks = 0; ks < 4; ++ks) {
            bf16x8 a0 = *(const bf16x8*)(W1F + (size_t)((0 * 4 + ks) * 64 + lane) * 8);
            h0 = __builtin_amdgcn_mfma_f32_32x32x16_bf16(a0, bw[ks], h0, 0, 0, 0);
            bf16x8 a1 = *(const bf16x8*)(W1F + (size_t)((1 * 4 + ks) * 64 + lane) * 8);
            h1 = __builtin_amdgcn_mfma_f32_32x32x16_bf16(a1, bw[ks], h1, 0, 0, 0);
        }
        // silu of the 32 channels this lane holds: c(r) = (r&3)+8*(r>>2)+4*hi (+32 for h1)
        float sv[32];
#pragma unroll
        for (int r = 0; r < 16; ++r) {
            float x0 = h0[r];
            sv[r]      = 1.679f * x0 / (1.f + __expf(-x0));
            float x1 = h1[r];
            sv[16 + r] = 1.679f * x1 / (1.f + __expf(-x1));
        }
        // In-register B-fragment assembly: hfr[ks][j] = h[16ks + 8*hi + j][eLoc]
        uint4 fr[4];
#pragma unroll
        for (int ks = 0; ks < 4; ++ks) {
            const int vb = 8 * ks;
            float oa = hi ? sv[vb + 4] : sv[vb + 0];
            float ob = hi ? sv[vb + 5] : sv[vb + 1];
            float oc = hi ? sv[vb + 6] : sv[vb + 2];
            float od = hi ? sv[vb + 7] : sv[vb + 3];
            float sa = hi ? sv[vb + 0] : sv[vb + 4];
            float sb = hi ? sv[vb + 1] : sv[vb + 5];
            float sc = hi ? sv[vb + 2] : sv[vb + 6];
            float sd = hi ? sv[vb + 3] : sv[vb + 7];
            unsigned o0 = pk_bf16(oa, ob), o1 = pk_bf16(oc, od);
            unsigned s0 = pk_bf16(sa, sb), s1 = pk_bf16(sc, sd);
            unsigned r0 = (unsigned)__shfl_xor((int)s0, 32, 64);
            unsigned r1 = (unsigned)__shfl_xor((int)s1, 32, 64);
            fr[ks].x = hi ? r0 : o0;   // j0,j1
            fr[ks].y = hi ? r1 : o1;   // j2,j3
            fr[ks].z = hi ? o0 : r0;   // j4,j5
            fr[ks].w = hi ? o1 : r1;   // j6,j7
        }
        hfr0 = *(bf16x8*)&fr[0];
        hfr1 = *(bf16x8*)&fr[1];
        hfr2 = *(bf16x8*)&fr[2];
        hfr3 = *(bf16x8*)&fr[3];
    }

    // ---- accumulators ----
    float acc0[16];
    float t011[8];
    float t101[3][8];
#pragma unroll
    for (int r = 0; r < 16; ++r) acc0[r] = 0.f;
#pragma unroll
    for (int s = 0; s < 8; ++s) { t011[s] = 0.f; t101[0][s] = 0.f; t101[1][s] = 0.f; t101[2][s] = 0.f; }

#define WAITV2 asm volatile("s_waitcnt vmcnt(2)" ::: "memory")
#define WAITV0 asm volatile("s_waitcnt vmcnt(0)" ::: "memory")

    // epilogues: C row rv=(r&3)+8*(r>>2)+4*hi; w_out = rv&15 -> slot s = r&7; u-select = (r>=8)
#define EPI_W00(TT) { float cf = sA0 * CFld(TT);                                  \
        _Pragma("unroll") for (int r = 0; r < 16; ++r) acc0[r] += cf * Cv[r]; }
#define EPI_W110(TT) { float cf = CFld(TT); /* c = 32+(TT-32) = TT */             \
        _Pragma("unroll") for (int r = 0; r < 16; ++r) acc0[r] += cf * Cv[r]; }
#define EPI_W011(TT) { const int uu = 2 * ((TT) - 48);                            \
        float cf0 = CFld(uu), cf1 = CFld(uu + 1);                                 \
        _Pragma("unroll") for (int r = 0; r < 16; ++r)                            \
            t011[r & 7] += (r >= 8 ? cf1 : cf0) * Cv[r]; }
#define EPI_W101(TT) { const int dd = 48 + 6 * ((TT) - 64);                       \
        float d00 = CFld(dd + 0), d01 = CFld(dd + 1), d02 = CFld(dd + 2);         \
        float d10 = CFld(dd + 3), d11 = CFld(dd + 4), d12 = CFld(dd + 5);         \
        _Pragma("unroll") for (int r = 0; r < 16; ++r) { int s = r & 7;           \
            t101[0][s] += (r >= 8 ? d10 : d00) * Cv[r];                           \
            t101[1][s] += (r >= 8 ? d11 : d01) * Cv[r];                           \
            t101[2][s] += (r >= 8 ? d12 : d02) * Cv[r]; } }

#define EPI_ANY(TT) {                                                             \
        if ((TT) < 32)      { EPI_W00(TT) }                                       \
        else if ((TT) < 48) { EPI_W110(TT) }                                      \
        else if ((TT) < 64) { EPI_W011(TT) }                                      \
        else                { EPI_W101(TT) } }

#define DO_TILE(TT) {                                                             \
        const __bf16* tb = RING + (((TT) % 6) << 11) + (lane << 3);               \
        bf16x8 a0 = *(const bf16x8*)(tb);                                         \
        bf16x8 a1 = *(const bf16x8*)(tb + 512);                                   \
        bf16x8 a2 = *(const bf16x8*)(tb + 1024);                                  \
        bf16x8 a3 = *(const bf16x8*)(tb + 1536);                                  \
        f32x16 Cv;                                                                \
        Cv = __builtin_amdgcn_mfma_f32_32x32x16_bf16(a0, hfr0, Z16, 0, 0, 0);     \
        Cv = __builtin_amdgcn_mfma_f32_32x32x16_bf16(a1, hfr1, Cv, 0, 0, 0);      \
        Cv = __builtin_amdgcn_mfma_f32_32x32x16_bf16(a2, hfr2, Cv, 0, 0, 0);      \
        Cv = __builtin_amdgcn_mfma_f32_32x32x16_bf16(a3, hfr3, Cv, 0, 0, 0);      \
        EPI_ANY(TT); }

    __syncthreads();   // CF visible to all waves (also drains prologue staging)

    // Main loop: 36 iterations x 2 tiles, 6-slot ring (3 groups resident).
    // Steady state: outstanding = groups {i+1, i+2} (4 loads); WAITV2 retires group i.
    // Group i+2's slots were consumed at iter i-1 -> safe to overwrite after this barrier.
#pragma unroll
    for (int i = 0; i < 36; ++i) {
        if (i < 35) { WAITV2; } else { WAITV0; }
        __builtin_amdgcn_s_barrier();
        __builtin_amdgcn_sched_barrier(0);
        if (2 * i + 4 < N_TILES) { STAGE(2 * i + 4); STAGE(2 * i + 5); }
        __builtin_amdgcn_sched_barrier(0);
        DO_TILE(2 * i);
        DO_TILE(2 * i + 1);
    }

    // ---- output staging (stride 81 = conflict-free): out[e][0..31]=out0 ; [32+w*3+k]=out1 ----
    __syncthreads();   // all ring/CF reads done; reuse LDS as staging
    float* OST = smemf;
#pragma unroll
    for (int r = 0; r < 16; ++r) {
        int rv = (r & 3) + 8 * (r >> 2) + 4 * hi;
        OST[eLoc * 81 + rv] = acc0[r];
    }
#pragma unroll
    for (int s = 0; s < 8; ++s) {
        int w = (s & 3) + 8 * (s >> 2) + 4 * hi;
        float b011 = 0.125f * t011[s];   // pw011*ISQRT3 = 1/8
        OST[eLoc * 81 + 32 + w * 3 + 0] = f2v.y * b011 + s101 * t101[0][s];
        OST[eLoc * 81 + 32 + w * 3 + 1] = f2v.z * b011 + s101 * t101[1][s];
        OST[eLoc * 81 + 32 + w * 3 + 2] = f2v.w * b011 + s101 * t101[2][s];
    }
    __syncthreads();
    {
        float* og = out + (size_t)blockIdx.x * 10240;
        for (int i = tid; i < 10240; i += 256) {
            int el = i / 80;
            int j  = i - el * 80;
            og[i] = OST[el * 81 + j];
        }
    }
}

extern "C" void kernel_launch(void* const* d_in, const int* in_sizes, int n_in,
                              void* d_out, int out_size, void* d_ws, size_t ws_size,
                              hipStream_t stream) {
    const float* fea_in1 = (const float*)d_in[0];
    const float* fea_in2 = (const float*)d_in[1];
    const float* fea_w   = (const float*)d_in[2];
    const float* W1      = (const float*)d_in[3];
    const float* W2      = (const float*)d_in[4];
    __bf16* W2F = (__bf16*)d_ws;
    __bf16* W1F = (__bf16*)((char*)d_ws + (size_t)W2F_ELEMS * 2);

    equiconv_prep<<<73, 256, 0, stream>>>(W1, W2, W1F, W2F);
    equiconv_main<<<65536 / 128, 256, 0, stream>>>(fea_in1, fea_in2, fea_w, W2F, W1F, (float*)d_out);
}

// Round 11
// 114.270 us; speedup vs baseline: 1.3988x; 1.3988x over previous
//
#include <hip/hip_runtime.h>
#include <hip/hip_bf16.h>

typedef __attribute__((ext_vector_type(8)))  __bf16 bf16x8;
typedef __attribute__((ext_vector_type(16))) float  f32x16;

#define N_TILES   72          // 2304 / 32
#define W2F_ELEMS (72*4*64*8) // 147456 bf16 (tile = 2048 bf16 = 4096 B)
#define W1F_ELEMS (2*4*64*8)  // 4096 bf16

__device__ __forceinline__ void gload_lds16(const void* g, void* l) {
    __builtin_amdgcn_global_load_lds(
        (const __attribute__((address_space(1))) unsigned int*)g,
        (__attribute__((address_space(3))) unsigned int*)l, 16, 0, 0);
}

__device__ __forceinline__ unsigned pk_bf16(float a, float b) {
    unsigned r;
    asm("v_cvt_pk_bf16_f32 %0, %1, %2" : "=v"(r) : "v"(a), "v"(b));
    return r;
}

// ---------------- prep: pack W2^T/8 and W1^T/8 (bf16) in MFMA A-fragment order ----------------
// A-frag order: [tile][ks][lane][j] holds A[row = 32*tile + (lane&31)][k = 16*ks + 8*(lane>>5) + j]
// Blocks 0..71: tile t, fully coalesced W2 row reads. Block 72: W1F (tiny).
__global__ __launch_bounds__(256) void equiconv_prep(const float* __restrict__ W1,
                                                     const float* __restrict__ W2,
                                                     __bf16* __restrict__ W1F,
                                                     __bf16* __restrict__ W2F) {
    const int b = blockIdx.x;
    const int tid = threadIdx.x;
    if (b < 72) {
        const int c   = tid >> 2;          // W2 row 0..63
        const int grp = tid & 3;           // octet of columns
        const float* src = W2 + (size_t)c * 2304 + 32 * b + 8 * grp;
        float4 u0 = *(const float4*)src;
        float4 u1 = *(const float4*)(src + 4);
        const int ks  = c >> 4;
        const int hib = (c >> 3) & 1;
        const int j   = c & 7;
        __bf16* dst = W2F + ((size_t)(b * 4 + ks) * 64 + 32 * hib + 8 * grp) * 8 + j;
        dst[0 * 8] = (__bf16)(u0.x * 0.125f);
        dst[1 * 8] = (__bf16)(u0.y * 0.125f);
        dst[2 * 8] = (__bf16)(u0.z * 0.125f);
        dst[3 * 8] = (__bf16)(u0.w * 0.125f);
        dst[4 * 8] = (__bf16)(u1.x * 0.125f);
        dst[5 * 8] = (__bf16)(u1.y * 0.125f);
        dst[6 * 8] = (__bf16)(u1.z * 0.125f);
        dst[7 * 8] = (__bf16)(u1.w * 0.125f);
    } else {
        for (int i2 = tid; i2 < W1F_ELEMS; i2 += 256) {
            int j  = i2 & 7;
            int ln = (i2 >> 3) & 63;
            int ks = (i2 >> 9) & 3;
            int mt = i2 >> 11;
            int c  = 32 * mt + (ln & 31);      // W1 output col (0..63)
            int in = ks * 16 + 8 * (ln >> 5) + j;
            W1F[i2] = (__bf16)(W1[in * 64 + c] * 0.125f);
        }
    }
}

// ---------------- main fused kernel: 128 elements / block (4 waves x 32 elems) ----------------
// LDS 73728 B: [0 .. 6144) floats = 6-slot staging ring (3 pairs x 8192 B);
//              [6144 .. 18432) floats = CF[c=96][el=128] coefficient array
//                (address depends only on el -> wave reads broadcast, conflict-free).
// CF c-map: 0..31 = x1_0[u]; 32..47 = cb1[u]; 48..95 = x1_1 flat (3u+k).
// Output staging (after loop) reuses floats [0 .. 10368) as [el=128][81].
__global__ __launch_bounds__(256, 2) void equiconv_main(const float* __restrict__ fea_in1,
                                                        const float* __restrict__ fea_in2,
                                                        const float* __restrict__ fea_w,
                                                        const __bf16* __restrict__ W2F,
                                                        const __bf16* __restrict__ W1F,
                                                        float* __restrict__ out) {
    __shared__ __align__(16) float smemf[18432];   // 73728 B
    char* rgb = (char*)smemf;
    const char* w2b = (const char*)W2F;

    const int tid  = threadIdx.x;
    const int lane = tid & 63;
    const int wv   = tid >> 6;     // wave 0..3
    const int l31  = lane & 31;
    const int hi   = lane >> 5;    // half-wave
    const int eBlk = blockIdx.x * 128;
    const int eLoc = wv * 32 + l31;       // element owned by this lane (0..127)

    const int stoff = wv * 1024 + (lane << 4);   // this thread's 16B staging slice

    // ---- prologue prefetch: groups 0,1 (pairs P0,P1) ----
    gload_lds16(w2b + stoff,        rgb + stoff);
    gload_lds16(w2b + 4096 + stoff, rgb + 4096 + stoff);
    gload_lds16(w2b + 8192 + stoff, rgb + 8192 + stoff);
    gload_lds16(w2b + 12288 + stoff, rgb + 12288 + stoff);

    // ---- CF staging: thread el (<128) loads its element row, writes CF (2-way bank = free) ----
    if (tid < 128) {
        const float* r1 = fea_in1 + (size_t)(eBlk + tid) * 80;
#pragma unroll
        for (int q = 0; q < 8; ++q) {
            float4 v = *(const float4*)(r1 + 4 * q);
            smemf[6144 + (4 * q + 0) * 128 + tid] = v.x;
            smemf[6144 + (4 * q + 1) * 128 + tid] = v.y;
            smemf[6144 + (4 * q + 2) * 128 + tid] = v.z;
            smemf[6144 + (4 * q + 3) * 128 + tid] = v.w;
        }
        float xv[48];
#pragma unroll
        for (int q = 0; q < 12; ++q) {
            float4 v = *(const float4*)(r1 + 32 + 4 * q);
            xv[4 * q + 0] = v.x; xv[4 * q + 1] = v.y; xv[4 * q + 2] = v.z; xv[4 * q + 3] = v.w;
            smemf[6144 + (48 + 4 * q + 0) * 128 + tid] = v.x;
            smemf[6144 + (48 + 4 * q + 1) * 128 + tid] = v.y;
            smemf[6144 + (48 + 4 * q + 2) * 128 + tid] = v.z;
            smemf[6144 + (48 + 4 * q + 3) * 128 + tid] = v.w;
        }
        const float4 f2o = *(const float4*)(fea_in2 + (size_t)(eBlk + tid) * 4);
        const float c110 = 0.10206207261596577f; // pw110*ISQRT3 = sqrt(1/96)
#pragma unroll
        for (int u = 0; u < 16; ++u)
            smemf[6144 + (32 + u) * 128 + tid] =
                c110 * (xv[3 * u] * f2o.y + xv[3 * u + 1] * f2o.z + xv[3 * u + 2] * f2o.w);
    }

    // ---- per-lane x2 scalars ----
    const float4 f2v = *(const float4*)(fea_in2 + (size_t)(eBlk + eLoc) * 4);
    const float sA0  = 0.125f * f2v.x;               // pw00 * x2_0
    const float s101 = 0.17677669529663687f * f2v.x; // sqrt(1/32) * x2_0

    // ---- GEMM1: x[c][e] = sum_in (W1[in][c]/8) * feaw[e][in]; h = 1.679*silu(x) ----
    const f32x16 Z16 = {0,0,0,0,0,0,0,0,0,0,0,0,0,0,0,0};
    bf16x8 hfr0, hfr1, hfr2, hfr3;
    {
        bf16x8 bw[4];
        const float* pw = fea_w + (size_t)(eBlk + eLoc) * 64 + hi * 8;
#pragma unroll
        for (int ks = 0; ks < 4; ++ks) {
            float4 u0 = *(const float4*)(pw + ks * 16);
            float4 u1 = *(const float4*)(pw + ks * 16 + 4);
            bf16x8 b;
            b[0] = (__bf16)u0.x; b[1] = (__bf16)u0.y; b[2] = (__bf16)u0.z; b[3] = (__bf16)u0.w;
            b[4] = (__bf16)u1.x; b[5] = (__bf16)u1.y; b[6] = (__bf16)u1.z; b[7] = (__bf16)u1.w;
            bw[ks] = b;
        }
        f32x16 h0 = Z16, h1 = Z16;
#pragma unroll
        for (int ks = 0; ks < 4; ++ks) {
            bf16x8 a0 = *(const bf16x8*)(W1F + (size_t)((0 * 4 + ks) * 64 + lane) * 8);
            h0 = __builtin_amdgcn_mfma_f32_32x32x16_bf16(a0, bw[ks], h0, 0, 0, 0);
            bf16x8 a1 = *(const bf16x8*)(W1F + (size_t)((1 * 4 + ks) * 64 + lane) * 8);
            h1 = __builtin_amdgcn_mfma_f32_32x32x16_bf16(a1, bw[ks], h1, 0, 0, 0);
        }
        float sv[32];
#pragma unroll
        for (int r = 0; r < 16; ++r) {
            float x0 = h0[r];
            sv[r]      = 1.679f * x0 / (1.f + __expf(-x0));
            float x1 = h1[r];
            sv[16 + r] = 1.679f * x1 / (1.f + __expf(-x1));
        }
        // In-register B-fragment assembly: hfr[ks][j] = h[16ks + 8*hi + j][eLoc]
        uint4 fr[4];
#pragma unroll
        for (int ks = 0; ks < 4; ++ks) {
            const int vb = 8 * ks;
            float oa = hi ? sv[vb + 4] : sv[vb + 0];
            float ob = hi ? sv[vb + 5] : sv[vb + 1];
            float oc = hi ? sv[vb + 6] : sv[vb + 2];
            float od = hi ? sv[vb + 7] : sv[vb + 3];
            float sa = hi ? sv[vb + 0] : sv[vb + 4];
            float sb = hi ? sv[vb + 1] : sv[vb + 5];
            float sc = hi ? sv[vb + 2] : sv[vb + 6];
            float sd = hi ? sv[vb + 3] : sv[vb + 7];
            unsigned o0 = pk_bf16(oa, ob), o1 = pk_bf16(oc, od);
            unsigned s0 = pk_bf16(sa, sb), s1 = pk_bf16(sc, sd);
            unsigned r0 = (unsigned)__shfl_xor((int)s0, 32, 64);
            unsigned r1 = (unsigned)__shfl_xor((int)s1, 32, 64);
            fr[ks].x = hi ? r0 : o0;
            fr[ks].y = hi ? r1 : o1;
            fr[ks].z = hi ? o0 : r0;
            fr[ks].w = hi ? o1 : r1;
        }
        hfr0 = *(bf16x8*)&fr[0];
        hfr1 = *(bf16x8*)&fr[1];
        hfr2 = *(bf16x8*)&fr[2];
        hfr3 = *(bf16x8*)&fr[3];
    }

    // ---- accumulators ----
    float acc0[16];
    float t011[8];
    float t101[3][8];
#pragma unroll
    for (int r = 0; r < 16; ++r) acc0[r] = 0.f;
#pragma unroll
    for (int s = 0; s < 8; ++s) { t011[s] = 0.f; t101[0][s] = 0.f; t101[1][s] = 0.f; t101[2][s] = 0.f; }

#define WAITV2 asm volatile("s_waitcnt vmcnt(2)" ::: "memory")
#define WAITV0 asm volatile("s_waitcnt vmcnt(0)" ::: "memory")
#define SCHEDB __builtin_amdgcn_sched_barrier(0)

    // stage one 2-tile group from gsrc into ring pair at byte offset so
#define STAGE2(gsrc, so) {                                                        \
        gload_lds16((gsrc) + stoff,        rgb + (so) + stoff);                   \
        gload_lds16((gsrc) + 4096 + stoff, rgb + (so) + 4096 + stoff); }

    // compute Cv for tile at ring byte offset bo (runtime)
#define MFMA4(Cv, bo) {                                                           \
        const __bf16* tb = (const __bf16*)(rgb + (bo)) + (lane << 3);             \
        bf16x8 a0 = *(const bf16x8*)(tb);                                         \
        bf16x8 a1 = *(const bf16x8*)(tb + 512);                                   \
        bf16x8 a2 = *(const bf16x8*)(tb + 1024);                                  \
        bf16x8 a3 = *(const bf16x8*)(tb + 1536);                                  \
        Cv = __builtin_amdgcn_mfma_f32_32x32x16_bf16(a0, hfr0, Z16, 0, 0, 0);     \
        Cv = __builtin_amdgcn_mfma_f32_32x32x16_bf16(a1, hfr1, Cv, 0, 0, 0);      \
        Cv = __builtin_amdgcn_mfma_f32_32x32x16_bf16(a2, hfr2, Cv, 0, 0, 0);      \
        Cv = __builtin_amdgcn_mfma_f32_32x32x16_bf16(a3, hfr3, Cv, 0, 0, 0); }

#define ADV(x) { (x) = ((x) == 16384) ? 0u : (x) + 8192u; }

    const float* cfp = smemf + 6144 + eLoc;   // per-lane CF base; CF[c] = cfp[c<<7]

    __syncthreads();   // CF visible to all waves (drains prologue staging too)

    unsigned cur = 0, stg = 16384;
    const char* gs = w2b + 16384;   // global source of group 2

    // Phase A: tiles 0..47 -> acc0. cf = (t<32 ? sA0*CF[t] : CF[t])  [CF c-index = t]
    int cA = 0;
#pragma unroll 1
    for (int g = 0; g < 24; ++g) {
        WAITV2;
        __builtin_amdgcn_s_barrier();
        SCHEDB;
        STAGE2(gs, stg); gs += 8192; ADV(stg);
        SCHEDB;
        float cf0 = cfp[cA << 7];
        float cf1 = cfp[(cA + 1) << 7];
        if (g < 16) { cf0 *= sA0; cf1 *= sA0; }
        f32x16 Cv0, Cv1;
        MFMA4(Cv0, cur);
        MFMA4(Cv1, cur + 4096);
#pragma unroll
        for (int r = 0; r < 16; ++r) acc0[r] += cf0 * Cv0[r] + cf1 * Cv1[r];
        cA += 2; ADV(cur);
    }

    // Phase B: tiles 48..63 -> t011. per tile: uu = 2*(t-48); cf pair CF[uu],CF[uu+1]
    int cB = 0;
#pragma unroll 1
    for (int g = 0; g < 8; ++g) {
        WAITV2;
        __builtin_amdgcn_s_barrier();
        SCHEDB;
        STAGE2(gs, stg); gs += 8192; ADV(stg);
        SCHEDB;
        float b00 = cfp[cB << 7],       b01 = cfp[(cB + 1) << 7];
        float b10 = cfp[(cB + 2) << 7], b11 = cfp[(cB + 3) << 7];
        f32x16 Cv0, Cv1;
        MFMA4(Cv0, cur);
        MFMA4(Cv1, cur + 4096);
#pragma unroll
        for (int r = 0; r < 16; ++r) {
            t011[r & 7] += (r >= 8 ? b01 : b00) * Cv0[r] + (r >= 8 ? b11 : b10) * Cv1[r];
        }
        cB += 4; ADV(cur);
    }

    // Phase C: tiles 64..71 -> t101. per tile: dd = 48+6*(t-64); 6 coeffs CF[dd..dd+5]
    int cC = 48;
#pragma unroll 1
    for (int g = 0; g < 3; ++g) {
        WAITV2;
        __builtin_amdgcn_s_barrier();
        SCHEDB;
        if (g < 2) { STAGE2(gs, stg); gs += 8192; ADV(stg); }
        SCHEDB;
        float d00 = cfp[cC << 7],       d01 = cfp[(cC + 1) << 7],  d02 = cfp[(cC + 2) << 7];
        float d03 = cfp[(cC + 3) << 7], d04 = cfp[(cC + 4) << 7],  d05 = cfp[(cC + 5) << 7];
        float e00 = cfp[(cC + 6) << 7], e01 = cfp[(cC + 7) << 7],  e02 = cfp[(cC + 8) << 7];
        float e03 = cfp[(cC + 9) << 7], e04 = cfp[(cC + 10) << 7], e05 = cfp[(cC + 11) << 7];
        f32x16 Cv0, Cv1;
        MFMA4(Cv0, cur);
        MFMA4(Cv1, cur + 4096);
#pragma unroll
        for (int r = 0; r < 16; ++r) {
            int s = r & 7;
            t101[0][s] += (r >= 8 ? d03 : d00) * Cv0[r] + (r >= 8 ? e03 : e00) * Cv1[r];
            t101[1][s] += (r >= 8 ? d04 : d01) * Cv0[r] + (r >= 8 ? e04 : e01) * Cv1[r];
            t101[2][s] += (r >= 8 ? d05 : d02) * Cv0[r] + (r >= 8 ? e05 : e02) * Cv1[r];
        }
        cC += 12; ADV(cur);
    }
    {   // peeled final group (tiles 70,71): drain all
        WAITV0;
        __builtin_amdgcn_s_barrier();
        SCHEDB;
        float d00 = cfp[cC << 7],       d01 = cfp[(cC + 1) << 7],  d02 = cfp[(cC + 2) << 7];
        float d03 = cfp[(cC + 3) << 7], d04 = cfp[(cC + 4) << 7],  d05 = cfp[(cC + 5) << 7];
        float e00 = cfp[(cC + 6) << 7], e01 = cfp[(cC + 7) << 7],  e02 = cfp[(cC + 8) << 7];
        float e03 = cfp[(cC + 9) << 7], e04 = cfp[(cC + 10) << 7], e05 = cfp[(cC + 11) << 7];
        f32x16 Cv0, Cv1;
        MFMA4(Cv0, cur);
        MFMA4(Cv1, cur + 4096);
#pragma unroll
        for (int r = 0; r < 16; ++r) {
            int s = r & 7;
            t101[0][s] += (r >= 8 ? d03 : d00) * Cv0[r] + (r >= 8 ? e03 : e00) * Cv1[r];
            t101[1][s] += (r >= 8 ? d04 : d01) * Cv0[r] + (r >= 8 ? e04 : e01) * Cv1[r];
            t101[2][s] += (r >= 8 ? d05 : d02) * Cv0[r] + (r >= 8 ? e05 : e02) * Cv1[r];
        }
    }

    // ---- output staging (stride 81 = conflict-free): out[e][0..31]=out0 ; [32+w*3+k]=out1 ----
    __syncthreads();   // all ring/CF reads done; reuse LDS as staging
    float* OST = smemf;
#pragma unroll
    for (int r = 0; r < 16; ++r) {
        int rv = (r & 3) + 8 * (r >> 2) + 4 * hi;
        OST[eLoc * 81 + rv] = acc0[r];
    }
#pragma unroll
    for (int s = 0; s < 8; ++s) {
        int w = (s & 3) + 8 * (s >> 2) + 4 * hi;
        float b011 = 0.125f * t011[s];   // pw011*ISQRT3 = 1/8
        OST[eLoc * 81 + 32 + w * 3 + 0] = f2v.y * b011 + s101 * t101[0][s];
        OST[eLoc * 81 + 32 + w * 3 + 1] = f2v.z * b011 + s101 * t101[1][s];
        OST[eLoc * 81 + 32 + w * 3 + 2] = f2v.w * b011 + s101 * t101[2][s];
    }
    __syncthreads();
    {
        float* og = out + (size_t)blockIdx.x * 10240;
        for (int i = tid; i < 10240; i += 256) {
            int el = i / 80;
            int j  = i - el * 80;
            og[i] = OST[el * 81 + j];
        }
    }
}

extern "C" void kernel_launch(void* const* d_in, const int* in_sizes, int n_in,
                              void* d_out, int out_size, void* d_ws, size_t ws_size,
                              hipStream_t stream) {
    const float* fea_in1 = (const float*)d_in[0];
    const float* fea_in2 = (const float*)d_in[1];
    const float* fea_w   = (const float*)d_in[2];
    const float* W1      = (const float*)d_in[3];
    const float* W2      = (const float*)d_in[4];
    __bf16* W2F = (__bf16*)d_ws;
    __bf16* W1F = (__bf16*)((char*)d_ws + (size_t)W2F_ELEMS * 2);

    equiconv_prep<<<73, 256, 0, stream>>>(W1, W2, W1F, W2F);
    equiconv_main<<<65536 / 128, 256, 0, stream>>>(fea_in1, fea_in2, fea_w, W2F, W1F, (float*)d_out);
}